// Round 15
// baseline (547.018 us; speedup 1.0000x reference)
//
#include <hip/hip_runtime.h>
#include <stdint.h>

#define EPS 1e-7f

constexpr int N_NODES = 50000;
constexpr int N_EDGES = 1600000;
constexpr int BATCH = 64;
constexpr int EMB = 16;
constexpr int HID = 192;
constexpr int OUTF = 128;
constexpr int DEMO = 5;
constexpr int MODEL_DIM = 64;
constexpr int OUT_DIM = 2;

// XCD partitioning for CSR build write-locality: 8 XCDs.
constexpr int NPART = 8;
constexpr int PART_NODES = (N_NODES + NPART - 1) / NPART;  // 6250

// src-bucketing for gather L2 locality: 16 buckets of 3125 nodes (~1.2 MB of x each).
constexpr int NBKT = 16;
constexpr int BKT_DIV = (N_NODES + NBKT - 1) / NBKT;  // 3125
constexpr int NB2 = N_NODES * NBKT;                    // 800000 (dst,bucket) cells

// Generalized scan geometry over NB2 elements: chunks of 1024 (256 thr x 4 elem).
constexpr int SCAN2_CHUNK = 1024;
constexpr int NCHUNK2 = (NB2 + SCAN2_CHUNK - 1) / SCAN2_CHUNK;  // 782

typedef unsigned short bf16_t;
typedef short s8v __attribute__((ext_vector_type(8)));    // 8 bf16 (4 VGPRs) MFMA A/B frag
typedef float f4v __attribute__((ext_vector_type(4)));    // MFMA C/D frag

static __device__ __forceinline__ float bf2f(bf16_t u) {
  return __uint_as_float(((uint32_t)u) << 16);
}
static __device__ __forceinline__ bf16_t f2bf(float f) {  // round-to-nearest-even
  uint32_t b = __float_as_uint(f);
  return (bf16_t)((b + 0x7FFFu + ((b >> 16) & 1u)) >> 16);
}

// ---------------------------------------------------------------- layer 0 gather
__global__ void emb_gather(const int* __restrict__ idx, const float* __restrict__ emb,
                           bf16_t* __restrict__ x) {
  int t = blockIdx.x * blockDim.x + threadIdx.x;
  if (t >= N_NODES * EMB) return;
  int node = t / EMB, f = t % EMB;
  x[t] = f2bf(emb[idx[node] * EMB + f]);
}

// ---------------------------------------------------------------- CSR build
// hist2[d*16 + src/3125]: per-(dst, src-bucket) counts. XCD dst-partitioned for
// atomic/write locality (blockIdx&7 -> partition, round-robin XCD dispatch).
__global__ void hist2_kernel(const int* __restrict__ src, const int* __restrict__ dst,
                             int* __restrict__ hist2) {
  int part = blockIdx.x & (NPART - 1);
  int blk = blockIdx.x >> 3;
  int nthread = (gridDim.x >> 3) * blockDim.x;
  int lo = part * PART_NODES, hi = lo + PART_NODES;
  for (int e = blk * blockDim.x + threadIdx.x; e < N_EDGES; e += nthread) {
    int d = dst[e];
    if (d >= lo && d < hi) atomicAdd(&hist2[d * NBKT + src[e] / BKT_DIV], 1);
  }
}

// ---- 3-phase exclusive scan over NB2 = 800k (dst,bucket) cells ----
__global__ void chunk_sum2_kernel(const int* __restrict__ hist2, int* __restrict__ chunk_sum) {
  int t = threadIdx.x;
  int base = blockIdx.x * SCAN2_CHUNK + t * 4;
  int v = 0;
#pragma unroll
  for (int j = 0; j < 4; ++j) {
    int i = base + j;
    if (i < NB2) v += hist2[i];
  }
#pragma unroll
  for (int off = 32; off > 0; off >>= 1) v += __shfl_down(v, off);
  __shared__ int s[4];
  if ((t & 63) == 0) s[t >> 6] = v;
  __syncthreads();
  if (t == 0) chunk_sum[blockIdx.x] = s[0] + s[1] + s[2] + s[3];
}

__global__ void scan_chunks2_kernel(const int* __restrict__ chunk_sum,
                                    int* __restrict__ chunk_off) {
  __shared__ int s[1024];
  int t = threadIdx.x;
  int v = (t < NCHUNK2) ? chunk_sum[t] : 0;
  s[t] = v;
  __syncthreads();
  for (int off = 1; off < 1024; off <<= 1) {
    int u = (t >= off) ? s[t - off] : 0;
    __syncthreads();
    s[t] += u;
    __syncthreads();
  }
  if (t < NCHUNK2) chunk_off[t] = s[t] - v;  // exclusive
}

__global__ void chunk_scan_write2_kernel(const int* __restrict__ hist2,
                                         const int* __restrict__ chunk_off,
                                         int* __restrict__ cursor2,
                                         int* __restrict__ row_start) {
  __shared__ int s[256];
  int t = threadIdx.x;
  int base = blockIdx.x * SCAN2_CHUNK + t * 4;
  int local[4];
  int tsum = 0;
#pragma unroll
  for (int j = 0; j < 4; ++j) {
    int i = base + j;
    local[j] = (i < NB2) ? hist2[i] : 0;
    tsum += local[j];
  }
  s[t] = tsum;
  __syncthreads();
  for (int off = 1; off < 256; off <<= 1) {
    int u = (t >= off) ? s[t - off] : 0;
    __syncthreads();
    s[t] += u;
    __syncthreads();
  }
  int run = chunk_off[blockIdx.x] + s[t] - tsum;  // exclusive prefix of elem base
#pragma unroll
  for (int j = 0; j < 4; ++j) {
    int i = base + j;
    if (i < NB2) {
      cursor2[i] = run;
      if ((i & (NBKT - 1)) == 0) row_start[i / NBKT] = run;
      if (i == NB2 - 1) row_start[N_NODES] = run + local[j];
      run += local[j];
    }
  }
}

// scatter with per-(dst,bucket) cursors -> csr_src rows sorted by src-bucket.
__global__ void scatter_kernel(const int* __restrict__ src, const int* __restrict__ dst,
                               int* __restrict__ cursor2, int* __restrict__ csr_src) {
  int part = blockIdx.x & (NPART - 1);
  int blk = blockIdx.x >> 3;
  int nthread = (gridDim.x >> 3) * blockDim.x;
  int lo = part * PART_NODES, hi = lo + PART_NODES;
  for (int e = blk * blockDim.x + threadIdx.x; e < N_EDGES; e += nthread) {
    int d = dst[e];
    if (d >= lo && d < hi) {
      int s = src[e];
      int pos = atomicAdd(&cursor2[d * NBKT + s / BKT_DIV], 1);
      csr_src[pos] = s;
    }
  }
}

// ---------------------------------------------------------------- aggregation, layer 0 (D=16)
template <int TPN, int NPB>
__global__ void agg2_kernel(const uint32_t* __restrict__ x, const int* __restrict__ row_start,
                            const int* __restrict__ csr_src, uint32_t* __restrict__ out) {
  int f = threadIdx.x % TPN;
  int node = blockIdx.x * NPB + threadIdx.x / TPN;
  if (node >= N_NODES) return;
  int s0 = row_start[node], s1 = row_start[node + 1];
  float deps = (float)(s1 - s0) * EPS;
  uint32_t xv = x[(size_t)node * TPN + f];
  float a0 = __uint_as_float(xv << 16) + deps;
  float a1 = __uint_as_float(xv & 0xFFFF0000u) + deps;
  int e = s0;
  for (; e + 8 <= s1; e += 8) {
    int idx[8];
#pragma unroll
    for (int j = 0; j < 8; ++j) idx[j] = csr_src[e + j];
    uint32_t v[8];
#pragma unroll
    for (int j = 0; j < 8; ++j) v[j] = x[(size_t)idx[j] * TPN + f];
#pragma unroll
    for (int j = 0; j < 8; ++j) {
      a0 += fmaxf(__uint_as_float(v[j] << 16), 0.f);
      a1 += fmaxf(__uint_as_float(v[j] & 0xFFFF0000u), 0.f);
    }
  }
  for (; e < s1; ++e) {
    uint32_t v = x[(size_t)csr_src[e] * TPN + f];
    a0 += fmaxf(__uint_as_float(v << 16), 0.f);
    a1 += fmaxf(__uint_as_float(v & 0xFFFF0000u), 0.f);
  }
  out[(size_t)node * TPN + f] = (uint32_t)f2bf(a0) | ((uint32_t)f2bf(a1) << 16);
}

// ---------------------------------------------------------------- W prep: f32[K][N] -> bf16[N][K]
__global__ void wprep_kernel(const float* __restrict__ W, int K, int NOUT,
                             bf16_t* __restrict__ Wt) {
  int t = blockIdx.x * blockDim.x + threadIdx.x;
  if (t >= K * NOUT) return;
  int k = t / NOUT, n = t % NOUT;  // coalesced read
  Wt[(size_t)n * K + k] = f2bf(W[t]);
}

// ---------------------------------------------------------------- fused agg + MFMA GEMM (layers 1-3)
// Block = 384 threads = 16 nodes x 24 lanes. Phase 1: uint4 gather-agg (row-major x,
// bucket-sorted edge lists, unroll-8, 32-bit offset math) -> 16x192 bf16 tile in LDS
// (row padded to 200 bf16). Phase 2: 6 waves split the NT column tiles of
// out[16,NOUT] = tile @ Wt + b. Saves the aggbf round-trip.
constexpr int FU_TPN = 24;
constexpr int FU_NPB = 16;
constexpr int FU_LDR = 200;   // padded LDS row stride (bf16); 400 B, 16B-aligned
template <int NOUT, bool OUT_BF16>
__global__ void fused_agg_gemm(const uint4* __restrict__ x, const int* __restrict__ row_start,
                               const int* __restrict__ csr_src,
                               const bf16_t* __restrict__ Wt, const float* __restrict__ bias,
                               void* __restrict__ outp) {
  constexpr int K = 192;
  constexpr int ROW = 24;      // uint4 per node row (50000*24 = 1.2M < 2^31 -> 32-bit offsets)
  __shared__ bf16_t tile[FU_NPB * FU_LDR];

  // ---- phase 1: aggregation ----
  {
    int f = threadIdx.x % FU_TPN;
    int ln = threadIdx.x / FU_TPN;          // 0..15
    int node = blockIdx.x * FU_NPB + ln;    // grid covers exactly N_NODES
    int s0 = row_start[node], s1 = row_start[node + 1];
    float deps = (float)(s1 - s0) * EPS;
    uint4 xv = x[(uint32_t)(node * ROW + f)];
    float a[8];
    {
      uint32_t pk[4] = {xv.x, xv.y, xv.z, xv.w};
#pragma unroll
      for (int q = 0; q < 4; ++q) {
        a[2 * q]     = __uint_as_float(pk[q] << 16) + deps;
        a[2 * q + 1] = __uint_as_float(pk[q] & 0xFFFF0000u) + deps;
      }
    }
    int e = s0;
    for (; e + 8 <= s1; e += 8) {
      uint32_t off_[8];
#pragma unroll
      for (int j = 0; j < 8; ++j) off_[j] = (uint32_t)csr_src[e + j] * ROW + f;
      uint4 v[8];
#pragma unroll
      for (int j = 0; j < 8; ++j) v[j] = x[off_[j]];
#pragma unroll
      for (int j = 0; j < 8; ++j) {
        uint32_t pk[4] = {v[j].x, v[j].y, v[j].z, v[j].w};
#pragma unroll
        for (int q = 0; q < 4; ++q) {
          a[2 * q]     += fmaxf(__uint_as_float(pk[q] << 16), 0.f);
          a[2 * q + 1] += fmaxf(__uint_as_float(pk[q] & 0xFFFF0000u), 0.f);
        }
      }
    }
    for (; e < s1; ++e) {
      uint4 v = x[(uint32_t)csr_src[e] * ROW + f];
      uint32_t pk[4] = {v.x, v.y, v.z, v.w};
#pragma unroll
      for (int q = 0; q < 4; ++q) {
        a[2 * q]     += fmaxf(__uint_as_float(pk[q] << 16), 0.f);
        a[2 * q + 1] += fmaxf(__uint_as_float(pk[q] & 0xFFFF0000u), 0.f);
      }
    }
    uint4 o;
    o.x = (uint32_t)f2bf(a[0]) | ((uint32_t)f2bf(a[1]) << 16);
    o.y = (uint32_t)f2bf(a[2]) | ((uint32_t)f2bf(a[3]) << 16);
    o.z = (uint32_t)f2bf(a[4]) | ((uint32_t)f2bf(a[5]) << 16);
    o.w = (uint32_t)f2bf(a[6]) | ((uint32_t)f2bf(a[7]) << 16);
    *reinterpret_cast<uint4*>(&tile[ln * FU_LDR + f * 8]) = o;
  }
  __syncthreads();

  // ---- phase 2: GEMM on the LDS tile ----
  {
    constexpr int KT = K / 32;     // 6
    constexpr int NT = NOUT / 16;  // 12 or 8
    int wave = threadIdx.x >> 6;   // 0..5
    int lane = threadIdx.x & 63;
    int rlo = lane & 15;
    int kbase = (lane >> 4) * 8;

    s8v af[KT];
#pragma unroll
    for (int kt = 0; kt < KT; ++kt)
      af[kt] = *reinterpret_cast<const s8v*>(&tile[rlo * FU_LDR + kbase + kt * 32]);

    int r0 = (lane >> 4) * 4;
    for (int nt = wave; nt < NT; nt += 6) {
      const bf16_t* wp = Wt + ((size_t)(nt * 16 + rlo)) * K + kbase;
      f4v c = {0.f, 0.f, 0.f, 0.f};
#pragma unroll
      for (int kt = 0; kt < KT; ++kt) {
        s8v b = *(const s8v*)(wp + kt * 32);
        c = __builtin_amdgcn_mfma_f32_16x16x32_bf16(af[kt], b, c, 0, 0, 0);
      }
      int col = nt * 16 + rlo;
      float bv = bias[col];
#pragma unroll
      for (int r = 0; r < 4; ++r) {
        float v = c[r] + bv;
        size_t o = (size_t)(blockIdx.x * FU_NPB + r0 + r) * NOUT + col;
        if constexpr (OUT_BF16) ((bf16_t*)outp)[o] = f2bf(v);
        else                    ((float*)outp)[o] = v;
      }
    }
  }
}

// ---------------------------------------------------------------- VALU GEMM (layer 0, K=16)
template <int DIN, int DOUT, bool OUT_BF16>
__global__ void gemm_kernel(const bf16_t* __restrict__ in, const float* __restrict__ W,
                            const float* __restrict__ bias, void* __restrict__ outp) {
  constexpr int ROWS = 16;
  __shared__ bf16_t tile[ROWS * DIN];
  int c = threadIdx.x;  // 0..DOUT-1
  int base = blockIdx.x * ROWS;

  {
    const uint4* gsrc = reinterpret_cast<const uint4*>(in + (size_t)base * DIN);
    uint4* ldst = reinterpret_cast<uint4*>(tile);
    constexpr int NV = ROWS * DIN * 2 / 16;
    for (int i = threadIdx.x; i < NV; i += blockDim.x) ldst[i] = gsrc[i];
  }
  __syncthreads();

  float acc[ROWS];
  float bc = bias[c];
#pragma unroll
  for (int r = 0; r < ROWS; ++r) acc[r] = bc;

  for (int k0 = 0; k0 < DIN; k0 += 8) {
    float w[8];
#pragma unroll
    for (int j = 0; j < 8; ++j) w[j] = W[(size_t)(k0 + j) * DOUT + c];
#pragma unroll
    for (int r = 0; r < ROWS; ++r) {
      uint4 packed = *reinterpret_cast<const uint4*>(&tile[r * DIN + k0]);
      uint32_t pk[4] = {packed.x, packed.y, packed.z, packed.w};
#pragma unroll
      for (int q = 0; q < 4; ++q) {
        float lo = __uint_as_float(pk[q] << 16);
        float hi = __uint_as_float(pk[q] & 0xFFFF0000u);
        acc[r] = fmaf(lo, w[2 * q], acc[r]);
        acc[r] = fmaf(hi, w[2 * q + 1], acc[r]);
      }
    }
  }

#pragma unroll
  for (int r = 0; r < ROWS; ++r) {
    size_t o = (size_t)(base + r) * DOUT + c;
    if constexpr (OUT_BF16) ((bf16_t*)outp)[o] = f2bf(acc[r]);
    else                    ((float*)outp)[o] = acc[r];
  }
}

// ---------------------------------------------------------------- mean pool (batch sorted)
constexpr int POOL_CHUNK = 100;
__global__ void pool_kernel(const float* __restrict__ x, const int* __restrict__ batch,
                            float* __restrict__ gsum, int* __restrict__ gcnt) {
  int f = threadIdx.x;  // 0..127
  int start = blockIdx.x * POOL_CHUNK;
  if (start >= N_NODES) return;
  int end = min(start + POOL_CHUNK, N_NODES);
  int cur = batch[start];
  float acc = 0.f;
  int cnt = 0;
  for (int i = start; i < end; ++i) {
    int b = batch[i];
    if (b != cur) {
      atomicAdd(&gsum[cur * OUTF + f], acc);
      if (f == 0) atomicAdd(&gcnt[cur], cnt);
      acc = 0.f; cnt = 0; cur = b;
    }
    acc += x[(size_t)i * OUTF + f];
    cnt++;
  }
  atomicAdd(&gsum[cur * OUTF + f], acc);
  if (f == 0) atomicAdd(&gcnt[cur], cnt);
}

// ---------------------------------------------------------------- head MLP
__global__ void mlp_kernel(const float* __restrict__ gsum, const int* __restrict__ gcnt,
                           const float* __restrict__ demo,
                           const float* __restrict__ Wc1, const float* __restrict__ bc1,
                           const float* __restrict__ Wc2, const float* __restrict__ bc2,
                           float* __restrict__ out) {
  int b = blockIdx.x;   // 0..63
  int c = threadIdx.x;  // 0..63
  __shared__ float feats[OUTF + DEMO];
  float inv = 1.f / fmaxf((float)gcnt[b], 1.f);
  for (int k = c; k < OUTF; k += MODEL_DIM) feats[k] = gsum[b * OUTF + k] * inv;
  if (c < DEMO) feats[OUTF + c] = demo[b * DEMO + c];
  __syncthreads();
  float s = bc1[c];
#pragma unroll
  for (int k = 0; k < OUTF + DEMO; ++k) s = fmaf(feats[k], Wc1[k * MODEL_DIM + c], s);
  float h = fmaxf(s, 0.f);
  float o0 = h * Wc2[c * OUT_DIM + 0];
  float o1 = h * Wc2[c * OUT_DIM + 1];
#pragma unroll
  for (int off = 32; off > 0; off >>= 1) {
    o0 += __shfl_down(o0, off);
    o1 += __shfl_down(o1, off);
  }
  if (c == 0) {
    out[b * OUT_DIM + 0] = o0 + bc2[0];
    out[b * OUT_DIM + 1] = o1 + bc2[1];
  }
}

// ---------------------------------------------------------------- launch
extern "C" void kernel_launch(void* const* d_in, const int* in_sizes, int n_in,
                              void* d_out, int out_size, void* d_ws, size_t ws_size,
                              hipStream_t stream) {
  const int*   node_idx = (const int*)d_in[0];
  const int*   edge_index = (const int*)d_in[1];
  const int*   batch = (const int*)d_in[2];
  const float* demo = (const float*)d_in[3];
  const float* emb  = (const float*)d_in[4];
  const float* W0 = (const float*)d_in[5];  const float* b0 = (const float*)d_in[6];
  const float* W1 = (const float*)d_in[7];  const float* b1 = (const float*)d_in[8];
  const float* W2 = (const float*)d_in[9];  const float* b2 = (const float*)d_in[10];
  const float* W3 = (const float*)d_in[11]; const float* b3 = (const float*)d_in[12];
  const float* Wc1 = (const float*)d_in[13]; const float* bc1 = (const float*)d_in[14];
  const float* Wc2 = (const float*)d_in[15]; const float* bc2 = (const float*)d_in[16];
  const int* src = edge_index;
  const int* dst = edge_index + N_EDGES;
  float* out = (float*)d_out;

  char* ws = (char*)d_ws;
  size_t off = 0;
  auto alloc = [&](size_t bytes) {
    void* p = ws + off;
    off += (bytes + 255) & ~size_t(255);
    return p;
  };
  bf16_t* xbf     = (bf16_t*)alloc((size_t)N_NODES * HID * 2);   // ping
  bf16_t* xbf2    = (bf16_t*)alloc((size_t)N_NODES * HID * 2);   // pong
  bf16_t* xbf0    = (bf16_t*)alloc((size_t)N_NODES * EMB * 2);   // layer-0 features
  bf16_t* agg0    = (bf16_t*)alloc((size_t)N_NODES * EMB * 2);   // layer-0 agg out
  float*  x3      = (float*)alloc((size_t)N_NODES * OUTF * 4);
  int*   csr_src  = (int*)alloc((size_t)N_EDGES * 4);
  int*   hist2    = (int*)alloc((size_t)NB2 * 4);
  int*   cursor2  = (int*)alloc((size_t)NB2 * 4);
  int*   row_start= (int*)alloc((size_t)(N_NODES + 1) * 4);
  int*   chunk_sum= (int*)alloc((size_t)NCHUNK2 * 4);
  int*   chunk_off= (int*)alloc((size_t)NCHUNK2 * 4);
  float* gsum     = (float*)alloc((size_t)BATCH * OUTF * 4);
  int*   gcnt     = (int*)alloc((size_t)BATCH * 4);
  bf16_t* Wt1     = (bf16_t*)alloc((size_t)HID * HID * 2);
  bf16_t* Wt2     = (bf16_t*)alloc((size_t)HID * HID * 2);
  bf16_t* Wt3     = (bf16_t*)alloc((size_t)OUTF * HID * 2);

  hipMemsetAsync(hist2, 0, (size_t)NB2 * 4, stream);
  hipMemsetAsync(gsum, 0, (size_t)BATCH * OUTF * 4, stream);
  hipMemsetAsync(gcnt, 0, (size_t)BATCH * 4, stream);

  // weight prep (bf16 transpose) — tiny
  wprep_kernel<<<(HID * HID + 255) / 256, 256, 0, stream>>>(W1, HID, HID, Wt1);
  wprep_kernel<<<(HID * HID + 255) / 256, 256, 0, stream>>>(W2, HID, HID, Wt2);
  wprep_kernel<<<(HID * OUTF + 255) / 256, 256, 0, stream>>>(W3, HID, OUTF, Wt3);

  // CSR build: (dst,src-bucket) histogram -> 800k scan -> bucket-sorted scatter.
  hist2_kernel<<<NPART * 256, 256, 0, stream>>>(src, dst, hist2);
  chunk_sum2_kernel<<<NCHUNK2, 256, 0, stream>>>(hist2, chunk_sum);
  scan_chunks2_kernel<<<1, 1024, 0, stream>>>(chunk_sum, chunk_off);
  chunk_scan_write2_kernel<<<NCHUNK2, 256, 0, stream>>>(hist2, chunk_off, cursor2, row_start);
  scatter_kernel<<<NPART * 256, 256, 0, stream>>>(src, dst, cursor2, csr_src);

  constexpr int FU_GRID = N_NODES / FU_NPB;  // 3125

  // layer 0 (K=16, VALU path)
  emb_gather<<<(N_NODES * EMB + 255) / 256, 256, 0, stream>>>(node_idx, emb, xbf0);
  agg2_kernel<8, 32><<<(N_NODES + 31) / 32, 256, 0, stream>>>(
      (const uint32_t*)xbf0, row_start, csr_src, (uint32_t*)agg0);
  gemm_kernel<16, 192, true><<<N_NODES / 16, 192, 0, stream>>>(agg0, W0, b0, xbf);
  // layers 1-3: fused agg + MFMA GEMM
  fused_agg_gemm<192, true><<<FU_GRID, FU_TPN * FU_NPB, 0, stream>>>(
      (const uint4*)xbf, row_start, csr_src, Wt1, b1, xbf2);
  fused_agg_gemm<192, true><<<FU_GRID, FU_TPN * FU_NPB, 0, stream>>>(
      (const uint4*)xbf2, row_start, csr_src, Wt2, b2, xbf);
  fused_agg_gemm<128, false><<<FU_GRID, FU_TPN * FU_NPB, 0, stream>>>(
      (const uint4*)xbf, row_start, csr_src, Wt3, b3, x3);

  // pool + head
  pool_kernel<<<(N_NODES + POOL_CHUNK - 1) / POOL_CHUNK, OUTF, 0, stream>>>(x3, batch, gsum, gcnt);
  mlp_kernel<<<BATCH, MODEL_DIM, 0, stream>>>(gsum, gcnt, demo, Wc1, bc1, Wc2, bc2, out);
}

// Round 16
// 487.368 us; speedup vs baseline: 1.1224x; 1.1224x over previous
//
#include <hip/hip_runtime.h>
#include <stdint.h>

#define EPS 1e-7f

constexpr int N_NODES = 50000;
constexpr int N_EDGES = 1600000;
constexpr int BATCH = 64;
constexpr int EMB = 16;
constexpr int HID = 192;
constexpr int OUTF = 128;
constexpr int DEMO = 5;
constexpr int MODEL_DIM = 64;
constexpr int OUT_DIM = 2;

// XCD partitioning for CSR build write-locality: 8 XCDs.
constexpr int NPART = 8;
constexpr int PART_NODES = (N_NODES + NPART - 1) / NPART;  // 6250

// src-bucketing for gather L2 locality: 16 buckets of 3125 nodes (~1.2 MB of x each).
constexpr int NBKT = 16;
constexpr int BKT_DIV = (N_NODES + NBKT - 1) / NBKT;  // 3125
constexpr int NB2 = N_NODES * NBKT;                    // 800000 (dst,bucket) cells

// Generalized scan geometry over NB2 elements: chunks of 1024 (256 thr x 4 elem).
constexpr int SCAN2_CHUNK = 1024;
constexpr int NCHUNK2 = (NB2 + SCAN2_CHUNK - 1) / SCAN2_CHUNK;  // 782

typedef unsigned short bf16_t;
typedef unsigned short u16;
typedef short s8v __attribute__((ext_vector_type(8)));    // 8 bf16 (4 VGPRs) MFMA A/B frag
typedef float f4v __attribute__((ext_vector_type(4)));    // MFMA C/D frag

static __device__ __forceinline__ float bf2f(bf16_t u) {
  return __uint_as_float(((uint32_t)u) << 16);
}
static __device__ __forceinline__ bf16_t f2bf(float f) {  // round-to-nearest-even
  uint32_t b = __float_as_uint(f);
  return (bf16_t)((b + 0x7FFFu + ((b >> 16) & 1u)) >> 16);
}

// ---------------------------------------------------------------- layer 0 gather
__global__ void emb_gather(const int* __restrict__ idx, const float* __restrict__ emb,
                           bf16_t* __restrict__ x) {
  int t = blockIdx.x * blockDim.x + threadIdx.x;
  if (t >= N_NODES * EMB) return;
  int node = t / EMB, f = t % EMB;
  x[t] = f2bf(emb[idx[node] * EMB + f]);
}

// ---------------------------------------------------------------- CSR build
// hist2[d*16 + src/3125]: per-(dst, src-bucket) counts. XCD dst-partitioned for
// atomic/write locality (blockIdx&7 -> partition, round-robin XCD dispatch).
__global__ void hist2_kernel(const int* __restrict__ src, const int* __restrict__ dst,
                             int* __restrict__ hist2) {
  int part = blockIdx.x & (NPART - 1);
  int blk = blockIdx.x >> 3;
  int nthread = (gridDim.x >> 3) * blockDim.x;
  int lo = part * PART_NODES, hi = lo + PART_NODES;
  for (int e = blk * blockDim.x + threadIdx.x; e < N_EDGES; e += nthread) {
    int d = dst[e];
    if (d >= lo && d < hi) atomicAdd(&hist2[d * NBKT + src[e] / BKT_DIV], 1);
  }
}

// ---- 3-phase exclusive scan over NB2 = 800k (dst,bucket) cells ----
__global__ void chunk_sum2_kernel(const int* __restrict__ hist2, int* __restrict__ chunk_sum) {
  int t = threadIdx.x;
  int base = blockIdx.x * SCAN2_CHUNK + t * 4;
  int v = 0;
#pragma unroll
  for (int j = 0; j < 4; ++j) {
    int i = base + j;
    if (i < NB2) v += hist2[i];
  }
#pragma unroll
  for (int off = 32; off > 0; off >>= 1) v += __shfl_down(v, off);
  __shared__ int s[4];
  if ((t & 63) == 0) s[t >> 6] = v;
  __syncthreads();
  if (t == 0) chunk_sum[blockIdx.x] = s[0] + s[1] + s[2] + s[3];
}

__global__ void scan_chunks2_kernel(const int* __restrict__ chunk_sum,
                                    int* __restrict__ chunk_off) {
  __shared__ int s[1024];
  int t = threadIdx.x;
  int v = (t < NCHUNK2) ? chunk_sum[t] : 0;
  s[t] = v;
  __syncthreads();
  for (int off = 1; off < 1024; off <<= 1) {
    int u = (t >= off) ? s[t - off] : 0;
    __syncthreads();
    s[t] += u;
    __syncthreads();
  }
  if (t < NCHUNK2) chunk_off[t] = s[t] - v;  // exclusive
}

__global__ void chunk_scan_write2_kernel(const int* __restrict__ hist2,
                                         const int* __restrict__ chunk_off,
                                         int* __restrict__ cursor2,
                                         int* __restrict__ row_start) {
  __shared__ int s[256];
  int t = threadIdx.x;
  int base = blockIdx.x * SCAN2_CHUNK + t * 4;
  int local[4];
  int tsum = 0;
#pragma unroll
  for (int j = 0; j < 4; ++j) {
    int i = base + j;
    local[j] = (i < NB2) ? hist2[i] : 0;
    tsum += local[j];
  }
  s[t] = tsum;
  __syncthreads();
  for (int off = 1; off < 256; off <<= 1) {
    int u = (t >= off) ? s[t - off] : 0;
    __syncthreads();
    s[t] += u;
    __syncthreads();
  }
  int run = chunk_off[blockIdx.x] + s[t] - tsum;  // exclusive prefix of elem base
#pragma unroll
  for (int j = 0; j < 4; ++j) {
    int i = base + j;
    if (i < NB2) {
      cursor2[i] = run;
      if ((i & (NBKT - 1)) == 0) row_start[i / NBKT] = run;
      if (i == NB2 - 1) row_start[N_NODES] = run + local[j];
      run += local[j];
    }
  }
}

// scatter with per-(dst,bucket) cursors -> csr_src rows sorted by src-bucket.
// csr_src stored as uint16 (node ids < 65536) — halves the edge-stream bytes.
__global__ void scatter_kernel(const int* __restrict__ src, const int* __restrict__ dst,
                               int* __restrict__ cursor2, u16* __restrict__ csr_src) {
  int part = blockIdx.x & (NPART - 1);
  int blk = blockIdx.x >> 3;
  int nthread = (gridDim.x >> 3) * blockDim.x;
  int lo = part * PART_NODES, hi = lo + PART_NODES;
  for (int e = blk * blockDim.x + threadIdx.x; e < N_EDGES; e += nthread) {
    int d = dst[e];
    if (d >= lo && d < hi) {
      int s = src[e];
      int pos = atomicAdd(&cursor2[d * NBKT + s / BKT_DIV], 1);
      csr_src[pos] = (u16)s;
    }
  }
}

// ---------------------------------------------------------------- aggregation, layer 0 (D=16)
template <int TPN, int NPB>
__global__ void agg2_kernel(const uint32_t* __restrict__ x, const int* __restrict__ row_start,
                            const u16* __restrict__ csr_src, uint32_t* __restrict__ out) {
  int f = threadIdx.x % TPN;
  int node = blockIdx.x * NPB + threadIdx.x / TPN;
  if (node >= N_NODES) return;
  int s0 = row_start[node], s1 = row_start[node + 1];
  float deps = (float)(s1 - s0) * EPS;
  uint32_t xv = x[(size_t)node * TPN + f];
  float a0 = __uint_as_float(xv << 16) + deps;
  float a1 = __uint_as_float(xv & 0xFFFF0000u) + deps;
  int e = s0;
  for (; e + 8 <= s1; e += 8) {
    int idx[8];
#pragma unroll
    for (int j = 0; j < 8; ++j) idx[j] = csr_src[e + j];
    uint32_t v[8];
#pragma unroll
    for (int j = 0; j < 8; ++j) v[j] = x[(size_t)idx[j] * TPN + f];
#pragma unroll
    for (int j = 0; j < 8; ++j) {
      a0 += fmaxf(__uint_as_float(v[j] << 16), 0.f);
      a1 += fmaxf(__uint_as_float(v[j] & 0xFFFF0000u), 0.f);
    }
  }
  for (; e < s1; ++e) {
    uint32_t v = x[(size_t)csr_src[e] * TPN + f];
    a0 += fmaxf(__uint_as_float(v << 16), 0.f);
    a1 += fmaxf(__uint_as_float(v & 0xFFFF0000u), 0.f);
  }
  out[(size_t)node * TPN + f] = (uint32_t)f2bf(a0) | ((uint32_t)f2bf(a1) << 16);
}

// ---------------------------------------------------------------- W prep: f32[K][N] -> bf16[N][K]
__global__ void wprep_kernel(const float* __restrict__ W, int K, int NOUT,
                             bf16_t* __restrict__ Wt) {
  int t = blockIdx.x * blockDim.x + threadIdx.x;
  if (t >= K * NOUT) return;
  int k = t / NOUT, n = t % NOUT;  // coalesced read
  Wt[(size_t)n * K + k] = f2bf(W[t]);
}

// ---------------------------------------------------------------- fused agg + MFMA GEMM (layers 1-3)
// Block = 384 threads = 16 nodes x 24 lanes. Phase 1: uint4 gather-agg (row-major x,
// bucket-sorted uint16 edge lists, unroll-4 — R13 form; unroll-8 regressed occupancy
// in R15) -> 16x192 bf16 tile in LDS (row padded to 200 bf16). Phase 2: 6 waves
// split the NT column tiles of out[16,NOUT] = tile @ Wt + b.
constexpr int FU_TPN = 24;
constexpr int FU_NPB = 16;
constexpr int FU_LDR = 200;   // padded LDS row stride (bf16); 400 B, 16B-aligned
template <int NOUT, bool OUT_BF16>
__global__ void fused_agg_gemm(const uint4* __restrict__ x, const int* __restrict__ row_start,
                               const u16* __restrict__ csr_src,
                               const bf16_t* __restrict__ Wt, const float* __restrict__ bias,
                               void* __restrict__ outp) {
  constexpr int K = 192;
  constexpr int ROW = 24;      // uint4 per node row
  __shared__ bf16_t tile[FU_NPB * FU_LDR];

  // ---- phase 1: aggregation (R13 unroll-4 body) ----
  {
    int f = threadIdx.x % FU_TPN;
    int ln = threadIdx.x / FU_TPN;          // 0..15
    int node = blockIdx.x * FU_NPB + ln;    // grid covers exactly N_NODES
    int s0 = row_start[node], s1 = row_start[node + 1];
    float deps = (float)(s1 - s0) * EPS;
    uint4 xv = x[(size_t)node * ROW + f];
    float a[8];
    {
      uint32_t pk[4] = {xv.x, xv.y, xv.z, xv.w};
#pragma unroll
      for (int q = 0; q < 4; ++q) {
        a[2 * q]     = __uint_as_float(pk[q] << 16) + deps;
        a[2 * q + 1] = __uint_as_float(pk[q] & 0xFFFF0000u) + deps;
      }
    }
    int e = s0;
    for (; e + 4 <= s1; e += 4) {
      int idx[4];
#pragma unroll
      for (int j = 0; j < 4; ++j) idx[j] = csr_src[e + j];
      uint4 v[4];
#pragma unroll
      for (int j = 0; j < 4; ++j) v[j] = x[(size_t)idx[j] * ROW + f];
#pragma unroll
      for (int j = 0; j < 4; ++j) {
        uint32_t pk[4] = {v[j].x, v[j].y, v[j].z, v[j].w};
#pragma unroll
        for (int q = 0; q < 4; ++q) {
          a[2 * q]     += fmaxf(__uint_as_float(pk[q] << 16), 0.f);
          a[2 * q + 1] += fmaxf(__uint_as_float(pk[q] & 0xFFFF0000u), 0.f);
        }
      }
    }
    for (; e < s1; ++e) {
      uint4 v = x[(size_t)csr_src[e] * ROW + f];
      uint32_t pk[4] = {v.x, v.y, v.z, v.w};
#pragma unroll
      for (int q = 0; q < 4; ++q) {
        a[2 * q]     += fmaxf(__uint_as_float(pk[q] << 16), 0.f);
        a[2 * q + 1] += fmaxf(__uint_as_float(pk[q] & 0xFFFF0000u), 0.f);
      }
    }
    uint4 o;
    o.x = (uint32_t)f2bf(a[0]) | ((uint32_t)f2bf(a[1]) << 16);
    o.y = (uint32_t)f2bf(a[2]) | ((uint32_t)f2bf(a[3]) << 16);
    o.z = (uint32_t)f2bf(a[4]) | ((uint32_t)f2bf(a[5]) << 16);
    o.w = (uint32_t)f2bf(a[6]) | ((uint32_t)f2bf(a[7]) << 16);
    *reinterpret_cast<uint4*>(&tile[ln * FU_LDR + f * 8]) = o;
  }
  __syncthreads();

  // ---- phase 2: GEMM on the LDS tile ----
  {
    constexpr int KT = K / 32;     // 6
    constexpr int NT = NOUT / 16;  // 12 or 8
    int wave = threadIdx.x >> 6;   // 0..5
    int lane = threadIdx.x & 63;
    int rlo = lane & 15;
    int kbase = (lane >> 4) * 8;

    s8v af[KT];
#pragma unroll
    for (int kt = 0; kt < KT; ++kt)
      af[kt] = *reinterpret_cast<const s8v*>(&tile[rlo * FU_LDR + kbase + kt * 32]);

    int r0 = (lane >> 4) * 4;
    for (int nt = wave; nt < NT; nt += 6) {
      const bf16_t* wp = Wt + ((size_t)(nt * 16 + rlo)) * K + kbase;
      f4v c = {0.f, 0.f, 0.f, 0.f};
#pragma unroll
      for (int kt = 0; kt < KT; ++kt) {
        s8v b = *(const s8v*)(wp + kt * 32);
        c = __builtin_amdgcn_mfma_f32_16x16x32_bf16(af[kt], b, c, 0, 0, 0);
      }
      int col = nt * 16 + rlo;
      float bv = bias[col];
#pragma unroll
      for (int r = 0; r < 4; ++r) {
        float v = c[r] + bv;
        size_t o = (size_t)(blockIdx.x * FU_NPB + r0 + r) * NOUT + col;
        if constexpr (OUT_BF16) ((bf16_t*)outp)[o] = f2bf(v);
        else                    ((float*)outp)[o] = v;
      }
    }
  }
}

// ---------------------------------------------------------------- VALU GEMM (layer 0, K=16)
template <int DIN, int DOUT, bool OUT_BF16>
__global__ void gemm_kernel(const bf16_t* __restrict__ in, const float* __restrict__ W,
                            const float* __restrict__ bias, void* __restrict__ outp) {
  constexpr int ROWS = 16;
  __shared__ bf16_t tile[ROWS * DIN];
  int c = threadIdx.x;  // 0..DOUT-1
  int base = blockIdx.x * ROWS;

  {
    const uint4* gsrc = reinterpret_cast<const uint4*>(in + (size_t)base * DIN);
    uint4* ldst = reinterpret_cast<uint4*>(tile);
    constexpr int NV = ROWS * DIN * 2 / 16;
    for (int i = threadIdx.x; i < NV; i += blockDim.x) ldst[i] = gsrc[i];
  }
  __syncthreads();

  float acc[ROWS];
  float bc = bias[c];
#pragma unroll
  for (int r = 0; r < ROWS; ++r) acc[r] = bc;

  for (int k0 = 0; k0 < DIN; k0 += 8) {
    float w[8];
#pragma unroll
    for (int j = 0; j < 8; ++j) w[j] = W[(size_t)(k0 + j) * DOUT + c];
#pragma unroll
    for (int r = 0; r < ROWS; ++r) {
      uint4 packed = *reinterpret_cast<const uint4*>(&tile[r * DIN + k0]);
      uint32_t pk[4] = {packed.x, packed.y, packed.z, packed.w};
#pragma unroll
      for (int q = 0; q < 4; ++q) {
        float lo = __uint_as_float(pk[q] << 16);
        float hi = __uint_as_float(pk[q] & 0xFFFF0000u);
        acc[r] = fmaf(lo, w[2 * q], acc[r]);
        acc[r] = fmaf(hi, w[2 * q + 1], acc[r]);
      }
    }
  }

#pragma unroll
  for (int r = 0; r < ROWS; ++r) {
    size_t o = (size_t)(base + r) * DOUT + c;
    if constexpr (OUT_BF16) ((bf16_t*)outp)[o] = f2bf(acc[r]);
    else                    ((float*)outp)[o] = acc[r];
  }
}

// ---------------------------------------------------------------- mean pool (batch sorted)
constexpr int POOL_CHUNK = 100;
__global__ void pool_kernel(const float* __restrict__ x, const int* __restrict__ batch,
                            float* __restrict__ gsum, int* __restrict__ gcnt) {
  int f = threadIdx.x;  // 0..127
  int start = blockIdx.x * POOL_CHUNK;
  if (start >= N_NODES) return;
  int end = min(start + POOL_CHUNK, N_NODES);
  int cur = batch[start];
  float acc = 0.f;
  int cnt = 0;
  for (int i = start; i < end; ++i) {
    int b = batch[i];
    if (b != cur) {
      atomicAdd(&gsum[cur * OUTF + f], acc);
      if (f == 0) atomicAdd(&gcnt[cur], cnt);
      acc = 0.f; cnt = 0; cur = b;
    }
    acc += x[(size_t)i * OUTF + f];
    cnt++;
  }
  atomicAdd(&gsum[cur * OUTF + f], acc);
  if (f == 0) atomicAdd(&gcnt[cur], cnt);
}

// ---------------------------------------------------------------- head MLP
__global__ void mlp_kernel(const float* __restrict__ gsum, const int* __restrict__ gcnt,
                           const float* __restrict__ demo,
                           const float* __restrict__ Wc1, const float* __restrict__ bc1,
                           const float* __restrict__ Wc2, const float* __restrict__ bc2,
                           float* __restrict__ out) {
  int b = blockIdx.x;   // 0..63
  int c = threadIdx.x;  // 0..63
  __shared__ float feats[OUTF + DEMO];
  float inv = 1.f / fmaxf((float)gcnt[b], 1.f);
  for (int k = c; k < OUTF; k += MODEL_DIM) feats[k] = gsum[b * OUTF + k] * inv;
  if (c < DEMO) feats[OUTF + c] = demo[b * DEMO + c];
  __syncthreads();
  float s = bc1[c];
#pragma unroll
  for (int k = 0; k < OUTF + DEMO; ++k) s = fmaf(feats[k], Wc1[k * MODEL_DIM + c], s);
  float h = fmaxf(s, 0.f);
  float o0 = h * Wc2[c * OUT_DIM + 0];
  float o1 = h * Wc2[c * OUT_DIM + 1];
#pragma unroll
  for (int off = 32; off > 0; off >>= 1) {
    o0 += __shfl_down(o0, off);
    o1 += __shfl_down(o1, off);
  }
  if (c == 0) {
    out[b * OUT_DIM + 0] = o0 + bc2[0];
    out[b * OUT_DIM + 1] = o1 + bc2[1];
  }
}

// ---------------------------------------------------------------- launch
extern "C" void kernel_launch(void* const* d_in, const int* in_sizes, int n_in,
                              void* d_out, int out_size, void* d_ws, size_t ws_size,
                              hipStream_t stream) {
  const int*   node_idx = (const int*)d_in[0];
  const int*   edge_index = (const int*)d_in[1];
  const int*   batch = (const int*)d_in[2];
  const float* demo = (const float*)d_in[3];
  const float* emb  = (const float*)d_in[4];
  const float* W0 = (const float*)d_in[5];  const float* b0 = (const float*)d_in[6];
  const float* W1 = (const float*)d_in[7];  const float* b1 = (const float*)d_in[8];
  const float* W2 = (const float*)d_in[9];  const float* b2 = (const float*)d_in[10];
  const float* W3 = (const float*)d_in[11]; const float* b3 = (const float*)d_in[12];
  const float* Wc1 = (const float*)d_in[13]; const float* bc1 = (const float*)d_in[14];
  const float* Wc2 = (const float*)d_in[15]; const float* bc2 = (const float*)d_in[16];
  const int* src = edge_index;
  const int* dst = edge_index + N_EDGES;
  float* out = (float*)d_out;

  char* ws = (char*)d_ws;
  size_t off = 0;
  auto alloc = [&](size_t bytes) {
    void* p = ws + off;
    off += (bytes + 255) & ~size_t(255);
    return p;
  };
  bf16_t* xbf     = (bf16_t*)alloc((size_t)N_NODES * HID * 2);   // ping
  bf16_t* xbf2    = (bf16_t*)alloc((size_t)N_NODES * HID * 2);   // pong
  bf16_t* xbf0    = (bf16_t*)alloc((size_t)N_NODES * EMB * 2);   // layer-0 features
  bf16_t* agg0    = (bf16_t*)alloc((size_t)N_NODES * EMB * 2);   // layer-0 agg out
  float*  x3      = (float*)alloc((size_t)N_NODES * OUTF * 4);
  u16*   csr_src  = (u16*)alloc((size_t)N_EDGES * 2);
  int*   hist2    = (int*)alloc((size_t)NB2 * 4);
  int*   cursor2  = (int*)alloc((size_t)NB2 * 4);
  int*   row_start= (int*)alloc((size_t)(N_NODES + 1) * 4);
  int*   chunk_sum= (int*)alloc((size_t)NCHUNK2 * 4);
  int*   chunk_off= (int*)alloc((size_t)NCHUNK2 * 4);
  float* gsum     = (float*)alloc((size_t)BATCH * OUTF * 4);
  int*   gcnt     = (int*)alloc((size_t)BATCH * 4);
  bf16_t* Wt1     = (bf16_t*)alloc((size_t)HID * HID * 2);
  bf16_t* Wt2     = (bf16_t*)alloc((size_t)HID * HID * 2);
  bf16_t* Wt3     = (bf16_t*)alloc((size_t)OUTF * HID * 2);

  hipMemsetAsync(hist2, 0, (size_t)NB2 * 4, stream);
  hipMemsetAsync(gsum, 0, (size_t)BATCH * OUTF * 4, stream);
  hipMemsetAsync(gcnt, 0, (size_t)BATCH * 4, stream);

  // weight prep (bf16 transpose) — tiny
  wprep_kernel<<<(HID * HID + 255) / 256, 256, 0, stream>>>(W1, HID, HID, Wt1);
  wprep_kernel<<<(HID * HID + 255) / 256, 256, 0, stream>>>(W2, HID, HID, Wt2);
  wprep_kernel<<<(HID * OUTF + 255) / 256, 256, 0, stream>>>(W3, HID, OUTF, Wt3);

  // CSR build: (dst,src-bucket) histogram -> 800k scan -> bucket-sorted scatter.
  hist2_kernel<<<NPART * 256, 256, 0, stream>>>(src, dst, hist2);
  chunk_sum2_kernel<<<NCHUNK2, 256, 0, stream>>>(hist2, chunk_sum);
  scan_chunks2_kernel<<<1, 1024, 0, stream>>>(chunk_sum, chunk_off);
  chunk_scan_write2_kernel<<<NCHUNK2, 256, 0, stream>>>(hist2, chunk_off, cursor2, row_start);
  scatter_kernel<<<NPART * 256, 256, 0, stream>>>(src, dst, cursor2, csr_src);

  constexpr int FU_GRID = N_NODES / FU_NPB;  // 3125

  // layer 0 (K=16, VALU path)
  emb_gather<<<(N_NODES * EMB + 255) / 256, 256, 0, stream>>>(node_idx, emb, xbf0);
  agg2_kernel<8, 32><<<(N_NODES + 31) / 32, 256, 0, stream>>>(
      (const uint32_t*)xbf0, row_start, csr_src, (uint32_t*)agg0);
  gemm_kernel<16, 192, true><<<N_NODES / 16, 192, 0, stream>>>(agg0, W0, b0, xbf);
  // layers 1-3: fused agg + MFMA GEMM
  fused_agg_gemm<192, true><<<FU_GRID, FU_TPN * FU_NPB, 0, stream>>>(
      (const uint4*)xbf, row_start, csr_src, Wt1, b1, xbf2);
  fused_agg_gemm<192, true><<<FU_GRID, FU_TPN * FU_NPB, 0, stream>>>(
      (const uint4*)xbf2, row_start, csr_src, Wt2, b2, xbf);
  fused_agg_gemm<128, false><<<FU_GRID, FU_TPN * FU_NPB, 0, stream>>>(
      (const uint4*)xbf, row_start, csr_src, Wt3, b3, x3);

  // pool + head
  pool_kernel<<<(N_NODES + POOL_CHUNK - 1) / POOL_CHUNK, OUTF, 0, stream>>>(x3, batch, gsum, gcnt);
  mlp_kernel<<<BATCH, MODEL_DIM, 0, stream>>>(gsum, gcnt, demo, Wc1, bc1, Wc2, bc2, out);
}